// Round 1
// baseline (859.673 us; speedup 1.0000x reference)
//
#include <hip/hip_runtime.h>
#include <math.h>

// Problem constants (from reference): B=2, H=240, W=1216, ITER=3, NUM=9, CH=27
#define B_ 2
#define H_ 240
#define W_ 1216
#define CH_ 27
#define NUM_ 9
#define TX 32
#define TY 8
#define HALO_W (TX + 2)   // 34
#define HALO_H (TY + 2)   // 10
#define PIX_ (B_ * H_ * W_)  // 583680 per [B,H,W] image set

// One propagation iteration, with the 27 needed conv channels fused in.
// iter i uses conv output channels:
//   offsets: oc = i*18 + j          (j = 2n+c, n tap, c in {x,y})
//   aff:     oc = 54 + i*9 + n
__global__ __launch_bounds__(256) void dyspn_iter(
    const float* __restrict__ guide, const float* __restrict__ conv_w,
    const float* __restrict__ conv_b, const float* __restrict__ tap,
    const float* __restrict__ confidence, const float* __restrict__ sp_dep,
    const float* __restrict__ cur_in, float* __restrict__ out_cur,
    float* __restrict__ pred, float* __restrict__ feat,
    const float* __restrict__ input, int iter)
{
    __shared__ float sg[CH_ * HALO_H * HALO_W];  // 27*10*34*4B = 36.7 KB -> 4 blocks/CU

    const int tid = threadIdx.x;
    const int tileX0 = blockIdx.x * TX;
    const int tileY0 = blockIdx.y * TY;
    const int b = blockIdx.z;

    // Stage guide tile (with 1-px zero halo) into LDS.
    for (int idx = tid; idx < CH_ * HALO_H * HALO_W; idx += 256) {
        int ic  = idx / (HALO_H * HALO_W);
        int rem = idx % (HALO_H * HALO_W);
        int ly = rem / HALO_W;
        int lx = rem % HALO_W;
        int gy = tileY0 + ly - 1;
        int gx = tileX0 + lx - 1;
        float v = 0.f;
        if (gx >= 0 && gx < W_ && gy >= 0 && gy < H_)
            v = guide[((b * CH_ + ic) * H_ + gy) * W_ + gx];
        sg[idx] = v;
    }
    __syncthreads();

    const int tx = tid % TX;
    const int ty = tid / TX;
    const int x = tileX0 + tx;   // W=1216 = 38*32, H=240 = 30*8 -> always in range
    const int y = tileY0 + ty;

    const int oc0 = iter * 18;        // offset channel base
    const int oc1 = 54 + iter * NUM_; // aff channel base

    float acc[27];
    #pragma unroll
    for (int j = 0; j < 18; ++j) acc[j] = conv_b[oc0 + j];
    #pragma unroll
    for (int j = 0; j < 9; ++j)  acc[18 + j] = conv_b[oc1 + j];

    // conv: 27 in-ch x 9 taps x 27 out-ch = 6561 FMAs/thread
    for (int ic = 0; ic < CH_; ++ic) {
        float g[9];
        #pragma unroll
        for (int t = 0; t < 9; ++t) {
            int dy = t / 3, dx = t % 3;
            g[t] = sg[ic * (HALO_H * HALO_W) + (ty + dy) * HALO_W + (tx + dx)];
        }
        #pragma unroll
        for (int j = 0; j < 18; ++j) {
            const float* wp = conv_w + ((oc0 + j) * CH_ + ic) * 9;  // wave-uniform -> scalar loads
            #pragma unroll
            for (int t = 0; t < 9; ++t) acc[j] = fmaf(wp[t], g[t], acc[j]);
        }
        #pragma unroll
        for (int j = 0; j < 9; ++j) {
            const float* wp = conv_w + ((oc1 + j) * CH_ + ic) * 9;
            #pragma unroll
            for (int t = 0; t < 9; ++t) acc[18 + j] = fmaf(wp[t], g[t], acc[18 + j]);
        }
    }

    // softmax over the 9 aff channels
    float m = acc[18];
    #pragma unroll
    for (int n = 1; n < 9; ++n) m = fmaxf(m, acc[18 + n]);
    float a[9]; float s = 0.f;
    #pragma unroll
    for (int n = 0; n < 9; ++n) { a[n] = __expf(acc[18 + n] - m); s += a[n]; }
    const float inv_s = 1.f / s;

    // 9-tap bilinear sampling from cur (zeros padding, matches grid_sample semantics)
    const float* cur = cur_in + b * (H_ * W_);
    float agg = 0.f;
    #pragma unroll
    for (int n = 0; n < 9; ++n) {
        float px = acc[2 * n]     + tap[2 * n]     + (float)x;
        float py = acc[2 * n + 1] + tap[2 * n + 1] + (float)y;
        float x0f = floorf(px), y0f = floorf(py);
        float wx = px - x0f, wy = py - y0f;
        int x0 = (int)x0f, y0 = (int)y0f;
        bool vx0 = (x0 >= 0) && (x0 < W_);
        bool vx1 = (x0 + 1 >= 0) && (x0 + 1 < W_);
        bool vy0 = (y0 >= 0) && (y0 < H_);
        bool vy1 = (y0 + 1 >= 0) && (y0 + 1 < H_);
        int cx0 = min(max(x0, 0), W_ - 1), cx1 = min(max(x0 + 1, 0), W_ - 1);
        int cy0 = min(max(y0, 0), H_ - 1), cy1 = min(max(y0 + 1, 0), H_ - 1);
        float v00 = 0.f, v01 = 0.f, v10 = 0.f, v11 = 0.f;
        if (vy0) {
            const float* row = cur + cy0 * W_;
            if (vx0) v00 = row[cx0];
            if (vx1) v01 = row[cx1];
        }
        if (vy1) {
            const float* row = cur + cy1 * W_;
            if (vx0) v10 = row[cx0];
            if (vx1) v11 = row[cx1];
        }
        float val = (1.f - wy) * ((1.f - wx) * v00 + wx * v01)
                  +        wy  * ((1.f - wx) * v10 + wx * v11);
        agg = fmaf(val, a[n] * inv_s, agg);
    }

    const int pix = b * (H_ * W_) + y * W_ + x;
    float c  = confidence[pix];
    float sp = sp_dep[pix];
    float sgn = (sp > 0.f) ? 1.f : ((sp < 0.f) ? -1.f : 0.f);
    float conf = sgn / (1.f + __expf(-c));   // sigmoid(c) * sign(sp)
    float nc = (1.f - conf) * agg + conf * sp;

    out_cur[pix] = nc;
    if (pred) pred[pix] = nc;            // last iteration also writes pred
    if (feat) feat[pix] = input[pix];    // first iteration copies feat_init
}

extern "C" void kernel_launch(void* const* d_in, const int* in_sizes, int n_in,
                              void* d_out, int out_size, void* d_ws, size_t ws_size,
                              hipStream_t stream) {
    (void)in_sizes; (void)n_in; (void)out_size; (void)d_ws; (void)ws_size;
    const float* input      = (const float*)d_in[0];
    const float* guide      = (const float*)d_in[1];
    const float* sp_dep     = (const float*)d_in[2];
    const float* confidence = (const float*)d_in[3];
    const float* conv_w     = (const float*)d_in[4];
    const float* conv_b     = (const float*)d_in[5];
    const float* tap        = (const float*)d_in[6];

    float* out   = (float*)d_out;
    const int P  = PIX_;          // 583680
    float* pred  = out;           // [B,1,H,W]
    float* feat  = out + P;       // [B,1,H,W]
    float* inter = out + 2 * P;   // [ITER,B,1,H,W]

    dim3 grid(W_ / TX, H_ / TY, B_);  // 38 x 30 x 2
    dim3 block(TX * TY);              // 256

    for (int i = 0; i < 3; ++i) {
        const float* cur = (i == 0) ? input : (inter + (i - 1) * P);
        float* dst = inter + i * P;
        dyspn_iter<<<grid, block, 0, stream>>>(
            guide, conv_w, conv_b, tap, confidence, sp_dep,
            cur, dst,
            (i == 2) ? pred : nullptr,
            (i == 0) ? feat : nullptr,
            input, i);
    }
}

// Round 2
// 216.312 us; speedup vs baseline: 3.9742x; 3.9742x over previous
//
#include <hip/hip_runtime.h>
#include <math.h>

// Problem constants: B=2, H=240, W=1216, ITER=3, NUM=9, CH=27
#define B_ 2
#define H_ 240
#define W_ 1216
#define CH_ 27
#define NUM_ 9
#define PIX_ (B_ * H_ * W_)   // 583680
#define CHP 32                // channel pad for gt layout
#define CHL 40                // channel pad in LDS (bank stride 20 dwords -> 4-way max)
#define TX 32
#define TY 8
#define HALO_W (TX + 2)       // 34
#define HALO_H (TY + 2)       // 10

typedef __attribute__((ext_vector_type(8))) __bf16 bf16x8;
typedef __attribute__((ext_vector_type(16))) float f32x16;

// ---------------------------------------------------------------------------
// Pre-kernel 1: transpose guide [B,27,H,W] fp32 -> gt [B*H*W][32] bf16
// ---------------------------------------------------------------------------
__global__ __launch_bounds__(256) void transpose_guide(
    const float* __restrict__ guide, __bf16* __restrict__ gt)
{
    int pix = blockIdx.x * 256 + threadIdx.x;
    if (pix >= PIX_) return;
    int b = pix / (H_ * W_);
    int off = pix - b * (H_ * W_);   // y*W + x
    __align__(16) __bf16 tmp[CHP];
    const float* src = guide + (size_t)b * CH_ * H_ * W_ + off;
    #pragma unroll
    for (int ic = 0; ic < CH_; ++ic)
        tmp[ic] = (__bf16)src[(size_t)ic * (H_ * W_)];
    #pragma unroll
    for (int ic = CH_; ic < CHP; ++ic) tmp[ic] = (__bf16)0.f;
    bf16x8* dst = (bf16x8*)(gt + (size_t)pix * CHP);
    const bf16x8* s8 = (const bf16x8*)tmp;
    #pragma unroll
    for (int c = 0; c < 4; ++c) dst[c] = s8[c];
}

// ---------------------------------------------------------------------------
// Pre-kernel 2: swizzle conv_w into MFMA B-fragment lane order.
// wlin[iter][tap][ks][lane(64)][8] bf16.
// B[k][n] for 32x32x16: n = lane&31, k = (lane>>5)*8 + j; ic = ks*16 + k.
// oc map: n<18 -> iter*18+n (offsets), 18<=n<27 -> 54+iter*9+(n-18) (aff).
// ---------------------------------------------------------------------------
__global__ __launch_bounds__(256) void prep_weights(
    const float* __restrict__ conv_w, __bf16* __restrict__ wlin)
{
    int idx = blockIdx.x * 256 + threadIdx.x;
    if (idx >= 3 * 9 * 2 * 64) return;
    int lane = idx & 63;
    int grp = idx >> 6;         // (iter*9+tap)*2 + ks
    int ks = grp & 1;
    int tapi = (grp >> 1) % 9;
    int it = (grp >> 1) / 9;
    int n = lane & 31;
    int half = lane >> 5;
    __align__(16) __bf16 v8[8];
    #pragma unroll
    for (int j = 0; j < 8; ++j) {
        int ic = ks * 16 + half * 8 + j;
        float v = 0.f;
        if (ic < CH_ && n < CH_) {
            int oc = (n < 18) ? (it * 18 + n) : (54 + it * NUM_ + (n - 18));
            v = conv_w[(size_t)(oc * CH_ + ic) * 9 + tapi];
        }
        v8[j] = (__bf16)v;
    }
    *(bf16x8*)(wlin + (size_t)idx * 8) = *(const bf16x8*)v8;
}

// ---------------------------------------------------------------------------
// Main fused kernel (one per propagation iteration): 27-out-ch conv via MFMA
// (9 shifted K=32 GEMMs over the raw channel-major LDS tile), softmax,
// 9-tap bilinear propagation, confidence blend.
// ---------------------------------------------------------------------------
__global__ __launch_bounds__(256, 2) void dyspn_iter_mfma(
    const __bf16* __restrict__ gt, const __bf16* __restrict__ wlin,
    const float* __restrict__ conv_b, const float* __restrict__ tap,
    const float* __restrict__ confidence, const float* __restrict__ sp_dep,
    const float* __restrict__ cur_in, float* __restrict__ out_cur,
    float* __restrict__ pred, float* __restrict__ feat,
    const float* __restrict__ input, int iter)
{
    // union: sG (10*34*40 bf16 = 27200 B) then reused as sC (256*33 f32 = 33792 B)
    __shared__ __align__(16) char smem[256 * 33 * 4];
    __bf16* sG = (__bf16*)smem;
    float*  sC = (float*)smem;
    __shared__ float sBias[CH_ + 1];

    const int tid = threadIdx.x;
    const int lane = tid & 63;
    const int w = tid >> 6;          // wave id 0..3 -> rows 2w, 2w+1
    const int xl = lane & 31;
    const int half = lane >> 5;
    const int tileX0 = blockIdx.x * TX;
    const int tileY0 = blockIdx.y * TY;
    const int b = blockIdx.z;

    // --- stage biases ---
    if (tid < CH_) {
        int n = tid;
        int oc = (n < 18) ? (iter * 18 + n) : (54 + iter * NUM_ + (n - 18));
        sBias[tid] = conv_b[oc];
    }

    // --- stage guide tile (halo, zero OOB) as [10][34][CHL] bf16 ---
    for (int idx = tid; idx < HALO_H * HALO_W * 4; idx += 256) {
        int chunk = idx & 3;
        int p = idx >> 2;               // 0..339
        int row = p / HALO_W;
        int px = p - row * HALO_W;
        int gy = tileY0 + row - 1;
        int gx = tileX0 + px - 1;
        uint4 v = make_uint4(0, 0, 0, 0);
        if (gx >= 0 && gx < W_ && gy >= 0 && gy < H_) {
            size_t pg = (size_t)b * (H_ * W_) + (size_t)gy * W_ + gx;
            v = ((const uint4*)(gt + pg * CHP))[chunk];
        }
        *(uint4*)((char*)sG + ((size_t)(row * HALO_W + px) * CHL + chunk * 8) * 2) = v;
    }

    // --- B fragments into registers: 9 taps x 2 ksteps ---
    bf16x8 Bf[18];
    {
        const __bf16* wb = wlin + ((size_t)iter * 18 * 64 + lane) * 8;
        #pragma unroll
        for (int i = 0; i < 18; ++i)
            Bf[i] = *(const bf16x8*)(wb + (size_t)i * 64 * 8);
    }

    f32x16 acc0 = {0,0,0,0,0,0,0,0,0,0,0,0,0,0,0,0};
    f32x16 acc1 = {0,0,0,0,0,0,0,0,0,0,0,0,0,0,0,0};

    __syncthreads();

    // --- MFMA main loop: 24 ds_read_b128, 36 MFMAs per wave ---
    #pragma unroll
    for (int kw = 0; kw < 3; ++kw) {
        #pragma unroll
        for (int ks = 0; ks < 2; ++ks) {
            bf16x8 A4[4];
            #pragma unroll
            for (int d = 0; d < 4; ++d) {
                const __bf16* ap = sG + (size_t)((2 * w + d) * HALO_W + xl + kw) * CHL
                                 + ks * 16 + half * 8;
                A4[d] = *(const bf16x8*)ap;
            }
            #pragma unroll
            for (int kh = 0; kh < 3; ++kh) {
                int t = kh * 3 + kw;
                acc0 = __builtin_amdgcn_mfma_f32_32x32x16_bf16(A4[kh],     Bf[t * 2 + ks], acc0, 0, 0, 0);
                acc1 = __builtin_amdgcn_mfma_f32_32x32x16_bf16(A4[kh + 1], Bf[t * 2 + ks], acc1, 0, 0, 0);
            }
        }
    }

    __syncthreads();   // all sG reads done before aliased sC writes

    // --- scatter C to LDS: pixel-major [256][33] f32 ---
    // C/D layout 32x32: ch = lane&31, px_x = (reg&3) + 8*(reg>>2) + 4*(lane>>5)
    {
        int ch = xl;
        #pragma unroll
        for (int a = 0; a < 2; ++a) {
            const f32x16 A = a ? acc1 : acc0;
            int ra = 2 * w + a;
            #pragma unroll
            for (int r = 0; r < 16; ++r) {
                int px_x = (r & 3) + 8 * (r >> 2) + 4 * half;
                sC[(ra * 32 + px_x) * 33 + ch] = A[r];
            }
        }
    }

    __syncthreads();

    // --- epilogue: one thread per pixel ---
    const int x = tileX0 + (tid & 31);
    const int y = tileY0 + (tid >> 5);
    float v27[CH_];
    #pragma unroll
    for (int j = 0; j < CH_; ++j) v27[j] = sC[tid * 33 + j] + sBias[j];

    // softmax over aff channels 18..26
    float m = v27[18];
    #pragma unroll
    for (int n = 1; n < 9; ++n) m = fmaxf(m, v27[18 + n]);
    float a[9]; float s = 0.f;
    #pragma unroll
    for (int n = 0; n < 9; ++n) { a[n] = __expf(v27[18 + n] - m); s += a[n]; }
    const float inv_s = 1.f / s;

    const float* cur = cur_in + (size_t)b * (H_ * W_);
    float agg = 0.f;
    #pragma unroll
    for (int n = 0; n < 9; ++n) {
        float px = v27[2 * n]     + tap[2 * n]     + (float)x;
        float py = v27[2 * n + 1] + tap[2 * n + 1] + (float)y;
        float x0f = floorf(px), y0f = floorf(py);
        float wx = px - x0f, wy = py - y0f;
        int x0 = (int)x0f, y0 = (int)y0f;
        bool vx0 = (x0 >= 0) && (x0 < W_);
        bool vx1 = (x0 + 1 >= 0) && (x0 + 1 < W_);
        bool vy0 = (y0 >= 0) && (y0 < H_);
        bool vy1 = (y0 + 1 >= 0) && (y0 + 1 < H_);
        int cx0 = min(max(x0, 0), W_ - 1), cx1 = min(max(x0 + 1, 0), W_ - 1);
        int cy0 = min(max(y0, 0), H_ - 1), cy1 = min(max(y0 + 1, 0), H_ - 1);
        float v00 = 0.f, v01 = 0.f, v10 = 0.f, v11 = 0.f;
        if (vy0) {
            const float* row = cur + (size_t)cy0 * W_;
            if (vx0) v00 = row[cx0];
            if (vx1) v01 = row[cx1];
        }
        if (vy1) {
            const float* row = cur + (size_t)cy1 * W_;
            if (vx0) v10 = row[cx0];
            if (vx1) v11 = row[cx1];
        }
        float val = (1.f - wy) * ((1.f - wx) * v00 + wx * v01)
                  +        wy  * ((1.f - wx) * v10 + wx * v11);
        agg = fmaf(val, a[n] * inv_s, agg);
    }

    const int pix = b * (H_ * W_) + y * W_ + x;
    float c  = confidence[pix];
    float sp = sp_dep[pix];
    float sgn = (sp > 0.f) ? 1.f : ((sp < 0.f) ? -1.f : 0.f);
    float conf = sgn / (1.f + __expf(-c));
    float nc = (1.f - conf) * agg + conf * sp;

    out_cur[pix] = nc;
    if (pred) pred[pix] = nc;
    if (feat) feat[pix] = input[pix];
}

// ---------------------------------------------------------------------------
// Fallback (round-1 fp32 kernel) if workspace is too small
// ---------------------------------------------------------------------------
__global__ __launch_bounds__(256) void dyspn_iter_fp32(
    const float* __restrict__ guide, const float* __restrict__ conv_w,
    const float* __restrict__ conv_b, const float* __restrict__ tap,
    const float* __restrict__ confidence, const float* __restrict__ sp_dep,
    const float* __restrict__ cur_in, float* __restrict__ out_cur,
    float* __restrict__ pred, float* __restrict__ feat,
    const float* __restrict__ input, int iter)
{
    __shared__ float sg[CH_ * HALO_H * HALO_W];
    const int tid = threadIdx.x;
    const int tileX0 = blockIdx.x * TX;
    const int tileY0 = blockIdx.y * TY;
    const int b = blockIdx.z;
    for (int idx = tid; idx < CH_ * HALO_H * HALO_W; idx += 256) {
        int ic  = idx / (HALO_H * HALO_W);
        int rem = idx % (HALO_H * HALO_W);
        int ly = rem / HALO_W;
        int lx = rem % HALO_W;
        int gy = tileY0 + ly - 1;
        int gx = tileX0 + lx - 1;
        float v = 0.f;
        if (gx >= 0 && gx < W_ && gy >= 0 && gy < H_)
            v = guide[((b * CH_ + ic) * H_ + gy) * W_ + gx];
        sg[idx] = v;
    }
    __syncthreads();
    const int tx = tid % TX;
    const int ty = tid / TX;
    const int x = tileX0 + tx;
    const int y = tileY0 + ty;
    const int oc0 = iter * 18;
    const int oc1 = 54 + iter * NUM_;
    float acc[27];
    #pragma unroll
    for (int j = 0; j < 18; ++j) acc[j] = conv_b[oc0 + j];
    #pragma unroll
    for (int j = 0; j < 9; ++j)  acc[18 + j] = conv_b[oc1 + j];
    for (int ic = 0; ic < CH_; ++ic) {
        float g[9];
        #pragma unroll
        for (int t = 0; t < 9; ++t) {
            int dy = t / 3, dx = t % 3;
            g[t] = sg[ic * (HALO_H * HALO_W) + (ty + dy) * HALO_W + (tx + dx)];
        }
        #pragma unroll
        for (int j = 0; j < 18; ++j) {
            const float* wp = conv_w + ((oc0 + j) * CH_ + ic) * 9;
            #pragma unroll
            for (int t = 0; t < 9; ++t) acc[j] = fmaf(wp[t], g[t], acc[j]);
        }
        #pragma unroll
        for (int j = 0; j < 9; ++j) {
            const float* wp = conv_w + ((oc1 + j) * CH_ + ic) * 9;
            #pragma unroll
            for (int t = 0; t < 9; ++t) acc[18 + j] = fmaf(wp[t], g[t], acc[18 + j]);
        }
    }
    float m = acc[18];
    #pragma unroll
    for (int n = 1; n < 9; ++n) m = fmaxf(m, acc[18 + n]);
    float a[9]; float s = 0.f;
    #pragma unroll
    for (int n = 0; n < 9; ++n) { a[n] = __expf(acc[18 + n] - m); s += a[n]; }
    const float inv_s = 1.f / s;
    const float* cur = cur_in + b * (H_ * W_);
    float agg = 0.f;
    #pragma unroll
    for (int n = 0; n < 9; ++n) {
        float px = acc[2 * n]     + tap[2 * n]     + (float)x;
        float py = acc[2 * n + 1] + tap[2 * n + 1] + (float)y;
        float x0f = floorf(px), y0f = floorf(py);
        float wx = px - x0f, wy = py - y0f;
        int x0 = (int)x0f, y0 = (int)y0f;
        bool vx0 = (x0 >= 0) && (x0 < W_);
        bool vx1 = (x0 + 1 >= 0) && (x0 + 1 < W_);
        bool vy0 = (y0 >= 0) && (y0 < H_);
        bool vy1 = (y0 + 1 >= 0) && (y0 + 1 < H_);
        int cx0 = min(max(x0, 0), W_ - 1), cx1 = min(max(x0 + 1, 0), W_ - 1);
        int cy0 = min(max(y0, 0), H_ - 1), cy1 = min(max(y0 + 1, 0), H_ - 1);
        float v00 = 0.f, v01 = 0.f, v10 = 0.f, v11 = 0.f;
        if (vy0) {
            const float* row = cur + cy0 * W_;
            if (vx0) v00 = row[cx0];
            if (vx1) v01 = row[cx1];
        }
        if (vy1) {
            const float* row = cur + cy1 * W_;
            if (vx0) v10 = row[cx0];
            if (vx1) v11 = row[cx1];
        }
        float val = (1.f - wy) * ((1.f - wx) * v00 + wx * v01)
                  +        wy  * ((1.f - wx) * v10 + wx * v11);
        agg = fmaf(val, a[n] * inv_s, agg);
    }
    const int pix = b * (H_ * W_) + y * W_ + x;
    float c  = confidence[pix];
    float sp = sp_dep[pix];
    float sgn = (sp > 0.f) ? 1.f : ((sp < 0.f) ? -1.f : 0.f);
    float conf = sgn / (1.f + __expf(-c));
    float nc = (1.f - conf) * agg + conf * sp;
    out_cur[pix] = nc;
    if (pred) pred[pix] = nc;
    if (feat) feat[pix] = input[pix];
}

extern "C" void kernel_launch(void* const* d_in, const int* in_sizes, int n_in,
                              void* d_out, int out_size, void* d_ws, size_t ws_size,
                              hipStream_t stream) {
    (void)in_sizes; (void)n_in; (void)out_size;
    const float* input      = (const float*)d_in[0];
    const float* guide      = (const float*)d_in[1];
    const float* sp_dep     = (const float*)d_in[2];
    const float* confidence = (const float*)d_in[3];
    const float* conv_w     = (const float*)d_in[4];
    const float* conv_b     = (const float*)d_in[5];
    const float* tap        = (const float*)d_in[6];

    float* out   = (float*)d_out;
    const int P  = PIX_;
    float* pred  = out;
    float* feat  = out + P;
    float* inter = out + 2 * P;

    dim3 grid(W_ / TX, H_ / TY, B_);  // 38 x 30 x 2
    dim3 block(256);

    const size_t gt_bytes   = (size_t)PIX_ * CHP * 2;     // 37,355,520
    const size_t wlin_bytes = (size_t)3 * 9 * 2 * 64 * 8 * 2;

    if (ws_size >= gt_bytes + wlin_bytes) {
        __bf16* gt   = (__bf16*)d_ws;
        __bf16* wlin = (__bf16*)((char*)d_ws + gt_bytes);

        transpose_guide<<<(PIX_ + 255) / 256, 256, 0, stream>>>(guide, gt);
        prep_weights<<<(3 * 9 * 2 * 64 + 255) / 256, 256, 0, stream>>>(conv_w, wlin);

        for (int i = 0; i < 3; ++i) {
            const float* cur = (i == 0) ? input : (inter + (i - 1) * P);
            dyspn_iter_mfma<<<grid, block, 0, stream>>>(
                gt, wlin, conv_b, tap, confidence, sp_dep,
                cur, inter + i * P,
                (i == 2) ? pred : nullptr,
                (i == 0) ? feat : nullptr,
                input, i);
        }
    } else {
        for (int i = 0; i < 3; ++i) {
            const float* cur = (i == 0) ? input : (inter + (i - 1) * P);
            dyspn_iter_fp32<<<grid, block, 0, stream>>>(
                guide, conv_w, conv_b, tap, confidence, sp_dep,
                cur, inter + i * P,
                (i == 2) ? pred : nullptr,
                (i == 0) ? feat : nullptr,
                input, i);
        }
    }
}